// Round 6
// baseline (111.264 us; speedup 1.0000x reference)
//
#include <hip/hip_runtime.h>
#include <hip/hip_bf16.h>

typedef __bf16 bf16x8 __attribute__((ext_vector_type(8)));
typedef float  f32x16 __attribute__((ext_vector_type(16)));
typedef unsigned int u32;

constexpr int QN  = 128;   // query rows
constexpr int KN  = 2048;  // memory rows
constexpr int D5  = 768;
constexpr int ZD  = 24;    // per-token sub-dim
constexpr int KCH = 8;     // k's per block (one per pair-loop iter; wave owns q)

static __device__ __forceinline__ float max3f(float a, float b, float c) {
    return fmaxf(fmaxf(a, b), c);   // v_max3_f32
}

// 16-elem max: level-1 pairwise (8 two-src fmax, can source AGPRs directly),
// then a max3 tree on the 8 partials.
static __device__ __forceinline__ float redmax16(const f32x16& a) {
    float p0 = fmaxf(a[0],  a[1]);
    float p1 = fmaxf(a[2],  a[3]);
    float p2 = fmaxf(a[4],  a[5]);
    float p3 = fmaxf(a[6],  a[7]);
    float p4 = fmaxf(a[8],  a[9]);
    float p5 = fmaxf(a[10], a[11]);
    float p6 = fmaxf(a[12], a[13]);
    float p7 = fmaxf(a[14], a[15]);
    float q0 = max3f(p0, p1, p2);
    float q1 = max3f(p3, p4, p5);
    return max3f(q0, q1, fmaxf(p6, p7));
}

// R6 = R4 base (wave owns q, k-loop of 8, ONE pair's acc pair live at a time,
// proven 65% occupancy) + the per-pair cross-lane shfl_xor(32) pair replaced by
// a packed bf16x2 ds_write_b32 (fire-and-forget) and a batched vector epilogue.
__global__ __launch_bounds__(256, 8) void matcher_kernel(const float* __restrict__ tgt,
                                                         const float* __restrict__ mem,
                                                         float* __restrict__ out)
{
    // Per k: chunk0 = 64 lanes x 16B (d0-15), chunk1 = 64 lanes x 16B (d16-23 + zero pad).
    __shared__ __align__(16) __bf16 Kf[KCH * 1024];    // 16 KB
    // Per-wave packed-max buffer: 8 pairs x 64 words (XOR-swizzled columns).
    __shared__ __align__(16) u32 vbuf[4 * 512];        // 8 KB (total 24 KB -> 6 blk/CU)

    const int tid = threadIdx.x;
    const int kc  = blockIdx.x;   // 0..255
    const int qg  = blockIdx.y;   // 0..31
    const int k0  = kc * KCH;

    // ---- stage K chunk: fp32 -> bf16, MFMA fragment order (one item/thread) ----
    {
        const int kl = tid >> 5;
        const int s  = tid & 31;
        const float* src = mem + (size_t)(k0 + kl) * D5 + s * ZD;
        float tv[24];
#pragma unroll
        for (int j = 0; j < 6; ++j) ((float4*)tv)[j] = ((const float4*)src)[j];
        bf16x8 a, b, c, z;
#pragma unroll
        for (int j = 0; j < 8; ++j) {
            a[j] = (__bf16)tv[j];
            b[j] = (__bf16)tv[8 + j];
            c[j] = (__bf16)tv[16 + j];
            z[j] = (__bf16)0.0f;
        }
        __bf16* base = Kf + kl * 1024;
        *(bf16x8*)(base +        s * 8)       = a;  // chunk0, lane s      (d 0-7)
        *(bf16x8*)(base + (32 +  s) * 8)      = b;  // chunk0, lane s+32   (d 8-15)
        *(bf16x8*)(base + 512 +  s * 8)       = c;  // chunk1, lane s      (d 16-23)
        *(bf16x8*)(base + 512 + (32 + s) * 8) = z;  // chunk1, lane s+32   (pad)
    }

    // ---- per-wave Q fragments (registers, live across the whole k-loop) ----
    const int lane = tid & 63;
    const int wv   = tid >> 6;   // 0..3
    const int t    = lane & 31;
    const int h    = lane >> 5;
    const int q    = qg * 4 + wv;

    const float4* p4 = (const float4*)(tgt + (size_t)q * D5 + t * ZD);
    bf16x8 aQ0, aQ1;
    {
        float4 u0 = p4[2 * h], u1 = p4[2 * h + 1];  // d = h*8 .. h*8+7
        aQ0[0] = (__bf16)u0.x; aQ0[1] = (__bf16)u0.y; aQ0[2] = (__bf16)u0.z; aQ0[3] = (__bf16)u0.w;
        aQ0[4] = (__bf16)u1.x; aQ0[5] = (__bf16)u1.y; aQ0[6] = (__bf16)u1.z; aQ0[7] = (__bf16)u1.w;
        if (h == 0) {
            float4 w0 = p4[4], w1 = p4[5];          // d = 16..23
            aQ1[0] = (__bf16)w0.x; aQ1[1] = (__bf16)w0.y; aQ1[2] = (__bf16)w0.z; aQ1[3] = (__bf16)w0.w;
            aQ1[4] = (__bf16)w1.x; aQ1[5] = (__bf16)w1.y; aQ1[6] = (__bf16)w1.z; aQ1[7] = (__bf16)w1.w;
        } else {
#pragma unroll
            for (int j = 0; j < 8; ++j) aQ1[j] = (__bf16)0.0f; // d 24-31 pad
        }
    }

    // Loop-invariant zero C operand (no per-pair accumulator init).
    f32x16 zacc;
#pragma unroll
    for (int i = 0; i < 16; ++i) zacc[i] = 0.0f;

    __syncthreads();

    u32* vbw = vbuf + wv * 512;
    const int hbase = h * 32;

    // ---- pair loop: (q, k0+kl), ONE acc pair live at a time ----
#pragma unroll
    for (int kl = 0; kl < KCH; ++kl) {
        const __bf16* lb = Kf + kl * 1024 + lane * 8;
        bf16x8 bK0 = *(const bf16x8*)lb;
        bf16x8 bK1 = *(const bf16x8*)(lb + 512);

        // S[t][s]: A=Q (m=t), B=K (n=s)
        f32x16 accS = __builtin_amdgcn_mfma_f32_32x32x16_bf16(aQ0, bK0, zacc, 0, 0, 0);
        accS        = __builtin_amdgcn_mfma_f32_32x32x16_bf16(aQ1, bK1, accS, 0, 0, 0);
        // S^T[s][t]: A=K (m=s), B=Q (n=t)
        f32x16 accT = __builtin_amdgcn_mfma_f32_32x32x16_bf16(bK0, aQ0, zacc, 0, 0, 0);
        accT        = __builtin_amdgcn_mfma_f32_32x32x16_bf16(bK1, aQ1, accT, 0, 0, 0);

        // Per-lane HALF maxes (this h's rows only):
        //   m1 = partial max over t at s=lane&31 (axis=3), m2 = over s at t (axis=2)
        float m1 = redmax16(accS);
        float m2 = redmax16(accT);
        // pack 2xbf16 (truncate) -> one fire-and-forget ds_write_b32, no consumer
        u32 pk = (__float_as_uint(m1) & 0xFFFF0000u) | (__float_as_uint(m2) >> 16);
        vbw[(kl << 6) + hbase + (t ^ (kl << 2))] = pk;   // XOR-swizzled, conflict-free
    }

    // ---- batched epilogue (same wave; no barrier needed) ----
    {
        const int p = lane >> 3;         // pair 0..7
        const int e = lane & 7;          // 8 lanes per pair, 4 columns each
        const u32* g = vbw + (p << 6) + ((4 * e) ^ (p << 2));
        uint4 g0 = *(const uint4*)g;          // half0, cols 4e..4e+3 (XOR keeps 4-blocks)
        uint4 g1 = *(const uint4*)(g + 32);   // half1, same cols
        u32 w0[4] = {g0.x, g0.y, g0.z, g0.w};
        u32 w1[4] = {g1.x, g1.y, g1.z, g1.w};
        float sum = 0.0f;
#pragma unroll
        for (int i = 0; i < 4; ++i) {
            float a1 = __uint_as_float(w0[i] & 0xFFFF0000u);  // m1, half0
            float a2 = __uint_as_float(w0[i] << 16);          // m2, half0
            float b1 = __uint_as_float(w1[i] & 0xFFFF0000u);  // m1, half1
            float b2 = __uint_as_float(w1[i] << 16);          // m2, half1
            sum += fmaxf(a1, b1) + fmaxf(a2, b2);
        }
        sum += __shfl_xor(sum, 1);
        sum += __shfl_xor(sum, 2);
        sum += __shfl_xor(sum, 4);       // total of the pair's 64 maxes
        float r = 1.0f / (1.0f + __expf(-sum * (1.0f / 64.0f)));
        if (e == 0) {
            const int idx = q * KN + k0 + p;
            out[idx] = r;                 // output 0
            out[idx + QN * KN] = r;       // output 1 (tuple repeats score_p)
        }
    }
}

extern "C" void kernel_launch(void* const* d_in, const int* in_sizes, int n_in,
                              void* d_out, int out_size, void* d_ws, size_t ws_size,
                              hipStream_t stream)
{
    const float* tgt = (const float*)d_in[0];
    const float* mem = (const float*)d_in[1];
    float* out = (float*)d_out;
    dim3 grid(KN / KCH, QN / 4);
    matcher_kernel<<<grid, 256, 0, stream>>>(tgt, mem, out);
}

// Round 7
// 97.639 us; speedup vs baseline: 1.1395x; 1.1395x over previous
//
#include <hip/hip_runtime.h>
#include <hip/hip_bf16.h>

typedef __bf16 bf16x8 __attribute__((ext_vector_type(8)));
typedef float  f32x16 __attribute__((ext_vector_type(16)));

constexpr int QN  = 128;   // query rows
constexpr int KN  = 2048;  // memory rows
constexpr int D5  = 768;
constexpr int ZD  = 24;    // per-token sub-dim
constexpr int KCH = 8;     // k's per block (one per pair-loop iter; wave owns q)

static __device__ __forceinline__ float max3f(float a, float b, float c) {
    return fmaxf(fmaxf(a, b), c);   // v_max3_f32
}

// 16-element register max as a max3 tree (R4-proven)
static __device__ __forceinline__ float redmax16(const f32x16& a) {
    float x0 = max3f(a[0],  a[1],  a[2]);
    float x1 = max3f(a[3],  a[4],  a[5]);
    float x2 = max3f(a[6],  a[7],  a[8]);
    float x3 = max3f(a[9],  a[10], a[11]);
    float x4 = max3f(a[12], a[13], a[14]);
    float y0 = max3f(x0, x1, x2);
    float y1 = max3f(x3, x4, a[15]);
    return fmaxf(y0, y1);
}

// R7 = R4 skeleton (42 us) with the 4 MFMAs in ONE inline-asm block, operands
// pinned to arch VGPRs ("v" constraints). This removes all AGPR<->VGPR copy
// traffic (R5/R6 showed the compiler's AGPR allocation causes VALU copy storms)
// and pins the MFMA schedule. Trailing s_nop 7/7/3 (20 wait states) covers the
// 16-pass MFMA -> VALU-read hazard explicitly.
__global__ __launch_bounds__(256, 5) void matcher_kernel(const float* __restrict__ tgt,
                                                         const float* __restrict__ mem,
                                                         float* __restrict__ out)
{
    // Per k: chunk0 = 64 lanes x 16B (d0-15), chunk1 = 64 lanes x 16B (d16-23 + zero pad).
    __shared__ __align__(16) __bf16 Kf[KCH * 1024];    // 16 KB
    // Per-wave epilogue buffer: [pair][32 swizzled maxes].
    __shared__ float vbuf[4][KCH * 32];                // 4 KB  (total 20 KB)

    const int tid = threadIdx.x;
    const int kc  = blockIdx.x;   // 0..255
    const int qg  = blockIdx.y;   // 0..31
    const int k0  = kc * KCH;

    // ---- stage K chunk: fp32 -> bf16, MFMA fragment order (one item/thread) ----
    {
        const int kl = tid >> 5;
        const int s  = tid & 31;
        const float* src = mem + (size_t)(k0 + kl) * D5 + s * ZD;
        float tv[24];
#pragma unroll
        for (int j = 0; j < 6; ++j) ((float4*)tv)[j] = ((const float4*)src)[j];
        bf16x8 a, b, c, z;
#pragma unroll
        for (int j = 0; j < 8; ++j) {
            a[j] = (__bf16)tv[j];
            b[j] = (__bf16)tv[8 + j];
            c[j] = (__bf16)tv[16 + j];
            z[j] = (__bf16)0.0f;
        }
        __bf16* base = Kf + kl * 1024;
        *(bf16x8*)(base +        s * 8)       = a;  // chunk0, lane s      (d 0-7)
        *(bf16x8*)(base + (32 +  s) * 8)      = b;  // chunk0, lane s+32   (d 8-15)
        *(bf16x8*)(base + 512 +  s * 8)       = c;  // chunk1, lane s      (d 16-23)
        *(bf16x8*)(base + 512 + (32 + s) * 8) = z;  // chunk1, lane s+32   (pad)
    }

    // ---- per-wave Q fragments (registers, live across the whole k-loop) ----
    const int lane = tid & 63;
    const int wv   = tid >> 6;   // 0..3
    const int t    = lane & 31;
    const int h    = lane >> 5;
    const int q    = qg * 4 + wv;

    const float4* p4 = (const float4*)(tgt + (size_t)q * D5 + t * ZD);
    bf16x8 aQ0, aQ1;
    {
        float4 u0 = p4[2 * h], u1 = p4[2 * h + 1];  // d = h*8 .. h*8+7
        aQ0[0] = (__bf16)u0.x; aQ0[1] = (__bf16)u0.y; aQ0[2] = (__bf16)u0.z; aQ0[3] = (__bf16)u0.w;
        aQ0[4] = (__bf16)u1.x; aQ0[5] = (__bf16)u1.y; aQ0[6] = (__bf16)u1.z; aQ0[7] = (__bf16)u1.w;
        if (h == 0) {
            float4 w0 = p4[4], w1 = p4[5];          // d = 16..23
            aQ1[0] = (__bf16)w0.x; aQ1[1] = (__bf16)w0.y; aQ1[2] = (__bf16)w0.z; aQ1[3] = (__bf16)w0.w;
            aQ1[4] = (__bf16)w1.x; aQ1[5] = (__bf16)w1.y; aQ1[6] = (__bf16)w1.z; aQ1[7] = (__bf16)w1.w;
        } else {
#pragma unroll
            for (int j = 0; j < 8; ++j) aQ1[j] = (__bf16)0.0f; // d 24-31 pad
        }
    }

    // Zero C operand, pinned to VGPRs by the asm "v" constraint.
    f32x16 zacc;
#pragma unroll
    for (int i = 0; i < 16; ++i) zacc[i] = 0.0f;

    __syncthreads();

    float* vb = vbuf[wv];

    // ---- pair loop: (q, k0+kl), ONE acc pair live at a time ----
#pragma unroll
    for (int kl = 0; kl < KCH; ++kl) {
        const __bf16* lb = Kf + kl * 1024 + lane * 8;
        bf16x8 bK0 = *(const bf16x8*)lb;
        bf16x8 bK1 = *(const bf16x8*)(lb + 512);

        // S = Q*K^T (m=t,n=s) and S^T = K*Q^T (m=s,n=t), all operands/results
        // in arch VGPRs. Back-to-back same-acc MFMA uses HW srcC forwarding.
        f32x16 accS, accT;
        asm("v_mfma_f32_32x32x16_bf16 %0, %2, %4, %6\n\t"
            "v_mfma_f32_32x32x16_bf16 %0, %3, %5, %0\n\t"
            "v_mfma_f32_32x32x16_bf16 %1, %4, %2, %6\n\t"
            "v_mfma_f32_32x32x16_bf16 %1, %5, %3, %1\n\t"
            "s_nop 7\n\t"
            "s_nop 7\n\t"
            "s_nop 3"
            : "=&v"(accS), "=&v"(accT)
            : "v"(aQ0), "v"(aQ1), "v"(bK0), "v"(bK1), "v"(zacc));

        // accS: col=s=lane&31, regs+halves span t -> max over t = score.max(axis=3)
        // accT: col=t=lane&31, regs+halves span s -> max over s = score.max(axis=2)
        float m1 = redmax16(accS);
        float m2 = redmax16(accT);
        m1 = fmaxf(m1, __shfl_xor(m1, 32));   // two INDEPENDENT half-combines
        m2 = fmaxf(m2, __shfl_xor(m2, 32));
        float v = m1 + m2;                    // per-lane: axis3max[s] + axis2max[t]
        // XOR-swizzled store: pair kl, slot t -> word kl*32 + (t^kl). Conflict-free.
        if (h == 0) vb[(kl << 5) + (t ^ kl)] = v;
    }

    // ---- batched final phase (per wave, no barrier: same-wave LDS reuse) ----
    // Pair p (0..7) summed by lanes (p, p+8): each reads 16 swizzled values.
    {
        const int p = lane & 7;
        const int g = (lane >> 3) & 1;
        float x[16];
#pragma unroll
        for (int i = 0; i < 16; ++i)
            x[i] = vb[(p << 5) + (((g << 4) + i) ^ p)];
        float s0 = (x[0] + x[1]) + (x[2] + x[3]);
        float s1 = (x[4] + x[5]) + (x[6] + x[7]);
        float s2 = (x[8] + x[9]) + (x[10] + x[11]);
        float s3 = (x[12] + x[13]) + (x[14] + x[15]);
        float sum = (s0 + s1) + (s2 + s3);
        sum += __shfl_xor(sum, 8);            // combine the two 16-halves
        float r = 1.0f / (1.0f + __expf(-sum * (1.0f / 64.0f)));
        if (lane < 8) {
            const int idx = q * KN + k0 + p;
            out[idx] = r;                     // output 0
            out[idx + QN * KN] = r;           // output 1 (tuple repeats score_p)
        }
    }
}

extern "C" void kernel_launch(void* const* d_in, const int* in_sizes, int n_in,
                              void* d_out, int out_size, void* d_ws, size_t ws_size,
                              hipStream_t stream)
{
    const float* tgt = (const float*)d_in[0];
    const float* mem = (const float*)d_in[1];
    float* out = (float*)d_out;
    dim3 grid(KN / KCH, QN / 4);
    matcher_kernel<<<grid, 256, 0, stream>>>(tgt, mem, out);
}